// Round 1
// baseline (778.210 us; speedup 1.0000x reference)
//
#include <hip/hip_runtime.h>

#define BB 64
#define PP 8732
#define NOBJ 16
#define NC 81
#define THRESH 0.5f
#define NEGPOS 3

__device__ __forceinline__ float smooth_l1(float x) {
    float ax = fabsf(x);
    return (ax < 1.0f) ? 0.5f * x * x : ax - 0.5f;
}

// ---------------- Kernel 1: per-batch matching + loc loss ----------------
__global__ __launch_bounds__(256) void k_match(
    const float* __restrict__ loc_data, const float* __restrict__ priors,
    const float* __restrict__ targets, unsigned char* __restrict__ conf_t,
    int* __restrict__ num_pos, double* __restrict__ accum)
{
    const int b = blockIdx.x;
    const int tid = threadIdx.x;

    __shared__ float s_tx1[NOBJ], s_ty1[NOBJ], s_tx2[NOBJ], s_ty2[NOBJ];
    __shared__ float s_lab[NOBJ], s_area[NOBJ];
    __shared__ unsigned long long s_best[NOBJ];
    __shared__ int s_bpi[NOBJ];

    if (tid < NOBJ) {
        const float* t = targets + ((size_t)b * NOBJ + tid) * 5;
        float x1 = t[0], y1 = t[1], x2 = t[2], y2 = t[3];
        s_tx1[tid] = x1; s_ty1[tid] = y1; s_tx2[tid] = x2; s_ty2[tid] = y2;
        s_lab[tid] = t[4];
        s_area[tid] = (x2 - x1) * (y2 - y1);
        s_best[tid] = 0ull;
    }
    __syncthreads();

    // ---- Phase A: per-truth best prior (argmax over p, ties -> smallest p) ----
    unsigned long long best[NOBJ];
    #pragma unroll
    for (int t = 0; t < NOBJ; ++t) best[t] = 0ull;

    for (int p = tid; p < PP; p += 256) {
        float4 pr = ((const float4*)priors)[p];
        float px1 = pr.x - pr.z * 0.5f, py1 = pr.y - pr.w * 0.5f;
        float px2 = pr.x + pr.z * 0.5f, py2 = pr.y + pr.w * 0.5f;
        float pa = (px2 - px1) * (py2 - py1);
        unsigned revp = 0xFFFFFFFFu - (unsigned)p;
        #pragma unroll
        for (int t = 0; t < NOBJ; ++t) {
            float ix1 = fmaxf(s_tx1[t], px1), iy1 = fmaxf(s_ty1[t], py1);
            float ix2 = fminf(s_tx2[t], px2), iy2 = fminf(s_ty2[t], py2);
            float iw = fmaxf(ix2 - ix1, 0.f), ih = fmaxf(iy2 - iy1, 0.f);
            float inter = iw * ih;
            float iou = inter / (s_area[t] + pa - inter);
            unsigned long long key =
                ((unsigned long long)__float_as_uint(iou) << 32) | revp;
            if (key > best[t]) best[t] = key;
        }
    }
    #pragma unroll
    for (int t = 0; t < NOBJ; ++t) atomicMax(&s_best[t], best[t]);
    __syncthreads();
    if (tid < NOBJ)
        s_bpi[tid] = (int)(0xFFFFFFFFu - (unsigned)(s_best[tid] & 0xFFFFFFFFull));
    __syncthreads();

    // ---- Phase B: per-prior best truth + overrides + loc loss ----
    int n_pos = 0;
    float lloss = 0.f;
    for (int p = tid; p < PP; p += 256) {
        float4 pr = ((const float4*)priors)[p];
        float px1 = pr.x - pr.z * 0.5f, py1 = pr.y - pr.w * 0.5f;
        float px2 = pr.x + pr.z * 0.5f, py2 = pr.y + pr.w * 0.5f;
        float pa = (px2 - px1) * (py2 - py1);
        float bt_ov = -1.f;
        int bt_idx = 0;
        #pragma unroll
        for (int t = 0; t < NOBJ; ++t) {
            float ix1 = fmaxf(s_tx1[t], px1), iy1 = fmaxf(s_ty1[t], py1);
            float ix2 = fminf(s_tx2[t], px2), iy2 = fminf(s_ty2[t], py2);
            float iw = fmaxf(ix2 - ix1, 0.f), ih = fmaxf(iy2 - iy1, 0.f);
            float inter = iw * ih;
            float iou = inter / (s_area[t] + pa - inter);
            if (iou > bt_ov) { bt_ov = iou; bt_idx = t; }  // strict >: first-max
        }
        // sequential last-wins override (matches numpy scatter)
        #pragma unroll
        for (int i = 0; i < NOBJ; ++i)
            if (s_bpi[i] == p) { bt_idx = i; bt_ov = 2.0f; }

        int c = (bt_ov < THRESH) ? 0 : ((int)s_lab[bt_idx] + 1);
        conf_t[(size_t)b * PP + p] = (unsigned char)c;

        if (c > 0) {
            n_pos++;
            float mx1 = s_tx1[bt_idx], my1 = s_ty1[bt_idx];
            float mx2 = s_tx2[bt_idx], my2 = s_ty2[bt_idx];
            float gcx = ((mx1 + mx2) * 0.5f - pr.x) / (0.1f * pr.z);
            float gcy = ((my1 + my2) * 0.5f - pr.y) / (0.1f * pr.w);
            float gw = logf((mx2 - mx1) / pr.z) / 0.2f;
            float gh = logf((my2 - my1) / pr.w) / 0.2f;
            float4 ld = ((const float4*)loc_data)[(size_t)b * PP + p];
            lloss += smooth_l1(ld.x - gcx) + smooth_l1(ld.y - gcy) +
                     smooth_l1(ld.z - gw) + smooth_l1(ld.w - gh);
        }
    }

    // block reduce n_pos, lloss
    for (int o = 32; o > 0; o >>= 1) {
        n_pos += __shfl_down(n_pos, o);
        lloss += __shfl_down(lloss, o);
    }
    __shared__ int s_np[4];
    __shared__ float s_ll[4];
    int wave = tid >> 6, lane = tid & 63;
    if (lane == 0) { s_np[wave] = n_pos; s_ll[wave] = lloss; }
    __syncthreads();
    if (tid == 0) {
        num_pos[b] = s_np[0] + s_np[1] + s_np[2] + s_np[3];
        atomicAdd(&accum[0], (double)(s_ll[0] + s_ll[1] + s_ll[2] + s_ll[3]));
    }
}

// ---------------- Kernel 2: conf loss per (b,p) ----------------
__global__ __launch_bounds__(256) void k_conf(
    const float* __restrict__ conf_data, const unsigned char* __restrict__ conf_t,
    float* __restrict__ lcm, double* __restrict__ accum)
{
    int idx = blockIdx.x * 256 + threadIdx.x;
    float posl = 0.f;
    if (idx < BB * PP) {
        const float* row = conf_data + (size_t)idx * NC;
        float m = row[0];
        for (int j = 1; j < NC; ++j) m = fmaxf(m, row[j]);
        float s = 0.f;
        for (int j = 0; j < NC; ++j) s += __expf(row[j] - m);
        float lse = m + __logf(s);
        int c = (int)conf_t[idx];
        float lc = lse - row[c];
        bool pos = (c > 0);
        lcm[idx] = pos ? 0.f : lc;
        posl = pos ? lc : 0.f;
    }
    for (int o = 32; o > 0; o >>= 1) posl += __shfl_down(posl, o);
    __shared__ float s_w[4];
    int wave = threadIdx.x >> 6, lane = threadIdx.x & 63;
    if (lane == 0) s_w[wave] = posl;
    __syncthreads();
    if (threadIdx.x == 0)
        atomicAdd(&accum[1], (double)(s_w[0] + s_w[1] + s_w[2] + s_w[3]));
}

// ---------------- Kernel 3: per-batch top-k sum (hard negative mining) ----
__global__ __launch_bounds__(256) void k_topk(
    const float* __restrict__ lcm, const int* __restrict__ num_pos,
    double* __restrict__ accum)
{
    __shared__ unsigned s_keys[PP];
    __shared__ int s_cnt;
    const int b = blockIdx.x, tid = threadIdx.x;
    for (int i = tid; i < PP; i += 256)
        s_keys[i] = __float_as_uint(lcm[(size_t)b * PP + i]);
    int k = NEGPOS * num_pos[b];
    if (k > PP - 1) k = PP - 1;
    __syncthreads();

    // MSB-greedy: find max T with count(key >= T) >= k  -> T = k-th largest
    unsigned T = 0;
    for (int bit = 31; bit >= 0; --bit) {
        unsigned cand = T | (1u << bit);
        int cnt = 0;
        for (int i = tid; i < PP; i += 256) cnt += (s_keys[i] >= cand) ? 1 : 0;
        for (int o = 32; o > 0; o >>= 1) cnt += __shfl_down(cnt, o);
        if (tid == 0) s_cnt = 0;
        __syncthreads();
        if ((tid & 63) == 0) atomicAdd(&s_cnt, cnt);
        __syncthreads();
        if (s_cnt >= k) T = cand;   // uniform decision across block
        __syncthreads();
    }

    // sum of top-k = sum(keys > T) + (k - count(keys > T)) * T
    float sum = 0.f;
    int cgt = 0;
    for (int i = tid; i < PP; i += 256) {
        unsigned kk = s_keys[i];
        if (kk > T) { sum += __uint_as_float(kk); cgt++; }
    }
    for (int o = 32; o > 0; o >>= 1) {
        sum += __shfl_down(sum, o);
        cgt += __shfl_down(cgt, o);
    }
    __shared__ float s_s[4];
    __shared__ int s_c[4];
    int wave = tid >> 6, lane = tid & 63;
    if (lane == 0) { s_s[wave] = sum; s_c[wave] = cgt; }
    __syncthreads();
    if (tid == 0) {
        float tot = s_s[0] + s_s[1] + s_s[2] + s_s[3];
        int ctot = s_c[0] + s_c[1] + s_c[2] + s_c[3];
        float neg = tot + (float)(k - ctot) * __uint_as_float(T);
        atomicAdd(&accum[1], (double)neg);
    }
}

// ---------------- Kernel 4: finalize ----------------
__global__ __launch_bounds__(64) void k_final(
    const int* __restrict__ num_pos, const double* __restrict__ accum,
    float* __restrict__ out)
{
    int tid = threadIdx.x;
    int n = (tid < BB) ? num_pos[tid] : 0;
    for (int o = 32; o > 0; o >>= 1) n += __shfl_down(n, o);
    if (tid == 0) {
        double N = (double)n;
        out[0] = (float)((accum[0] + accum[1]) / N);  // ALPHA = 1
    }
}

extern "C" void kernel_launch(void* const* d_in, const int* in_sizes, int n_in,
                              void* d_out, int out_size, void* d_ws, size_t ws_size,
                              hipStream_t stream) {
    const float* loc_data  = (const float*)d_in[0];
    const float* conf_data = (const float*)d_in[1];
    const float* priors    = (const float*)d_in[2];
    const float* targets   = (const float*)d_in[3];

    char* ws = (char*)d_ws;
    // layout: [0,16) double accum[2]; [16,16+256) int num_pos[64];
    //         [512, 512+BB*PP) u8 conf_t; then float lcm[BB*PP]
    double* accum = (double*)ws;
    int* num_pos = (int*)(ws + 16);
    unsigned char* conf_t = (unsigned char*)(ws + 512);
    float* lcm = (float*)(ws + 512 + (size_t)BB * PP);

    hipMemsetAsync(ws, 0, 512, stream);

    k_match<<<BB, 256, 0, stream>>>(loc_data, priors, targets, conf_t, num_pos, accum);

    int nblk = (BB * PP + 255) / 256;
    k_conf<<<nblk, 256, 0, stream>>>(conf_data, conf_t, lcm, accum);

    k_topk<<<BB, 256, 0, stream>>>(lcm, num_pos, accum);

    k_final<<<1, 64, 0, stream>>>(num_pos, accum, (float*)d_out);
}

// Round 2
// 394.231 us; speedup vs baseline: 1.9740x; 1.9740x over previous
//
#include <hip/hip_runtime.h>

#define BB 64
#define PP 8732
#define NOBJ 16
#define NC 81
#define THRESH 0.5f
#define NEGPOS 3
#define NCHUNK 4
#define CHUNK (PP / NCHUNK)   // 2183

__device__ __forceinline__ float smooth_l1(float x) {
    float ax = fabsf(x);
    return (ax < 1.0f) ? 0.5f * x * x : ax - 0.5f;
}

// ---------- Kernel 1A: per-truth best prior (global u64 atomicMax) ----------
__global__ __launch_bounds__(256) void k_matchA(
    const float* __restrict__ priors, const float* __restrict__ targets,
    unsigned long long* __restrict__ g_best)
{
    const int chunk = blockIdx.x;
    const int b = blockIdx.y;
    const int tid = threadIdx.x;

    __shared__ float s_tx1[NOBJ], s_ty1[NOBJ], s_tx2[NOBJ], s_ty2[NOBJ];
    __shared__ float s_area[NOBJ];
    __shared__ unsigned long long s_best[NOBJ];

    if (tid < NOBJ) {
        const float* t = targets + ((size_t)b * NOBJ + tid) * 5;
        float x1 = t[0], y1 = t[1], x2 = t[2], y2 = t[3];
        s_tx1[tid] = x1; s_ty1[tid] = y1; s_tx2[tid] = x2; s_ty2[tid] = y2;
        s_area[tid] = (x2 - x1) * (y2 - y1);
        s_best[tid] = 0ull;
    }
    __syncthreads();

    unsigned long long best[NOBJ];
    #pragma unroll
    for (int t = 0; t < NOBJ; ++t) best[t] = 0ull;

    const int p0 = chunk * CHUNK, p1 = p0 + CHUNK;
    for (int p = p0 + tid; p < p1; p += 256) {
        float4 pr = ((const float4*)priors)[p];
        float px1 = pr.x - pr.z * 0.5f, py1 = pr.y - pr.w * 0.5f;
        float px2 = pr.x + pr.z * 0.5f, py2 = pr.y + pr.w * 0.5f;
        float pa = (px2 - px1) * (py2 - py1);
        unsigned revp = 0xFFFFFFFFu - (unsigned)p;
        #pragma unroll
        for (int t = 0; t < NOBJ; ++t) {
            float ix1 = fmaxf(s_tx1[t], px1), iy1 = fmaxf(s_ty1[t], py1);
            float ix2 = fminf(s_tx2[t], px2), iy2 = fminf(s_ty2[t], py2);
            float iw = fmaxf(ix2 - ix1, 0.f), ih = fmaxf(iy2 - iy1, 0.f);
            float inter = iw * ih;
            float iou = inter / (s_area[t] + pa - inter);
            unsigned long long key =
                ((unsigned long long)__float_as_uint(iou) << 32) | revp;
            if (key > best[t]) best[t] = key;
        }
    }
    // wave reduce each truth's key, then LDS, then one global atomic per truth
    #pragma unroll
    for (int t = 0; t < NOBJ; ++t) {
        unsigned long long v = best[t];
        for (int o = 32; o > 0; o >>= 1) {
            unsigned long long w = __shfl_down(v, o);
            if (w > v) v = w;
        }
        if ((tid & 63) == 0) atomicMax(&s_best[t], v);
    }
    __syncthreads();
    if (tid < NOBJ) atomicMax(&g_best[b * NOBJ + tid], s_best[tid]);
}

// ---------- Kernel 1B: per-prior match + loc loss + conf_t ----------
__global__ __launch_bounds__(256) void k_matchB(
    const float* __restrict__ loc_data, const float* __restrict__ priors,
    const float* __restrict__ targets, const unsigned long long* __restrict__ g_best,
    unsigned char* __restrict__ conf_t, int* __restrict__ num_pos,
    double* __restrict__ accum)
{
    const int chunk = blockIdx.x;
    const int b = blockIdx.y;
    const int tid = threadIdx.x;

    __shared__ float s_tx1[NOBJ], s_ty1[NOBJ], s_tx2[NOBJ], s_ty2[NOBJ];
    __shared__ float s_lab[NOBJ], s_area[NOBJ];
    __shared__ int s_bpi[NOBJ];

    if (tid < NOBJ) {
        const float* t = targets + ((size_t)b * NOBJ + tid) * 5;
        float x1 = t[0], y1 = t[1], x2 = t[2], y2 = t[3];
        s_tx1[tid] = x1; s_ty1[tid] = y1; s_tx2[tid] = x2; s_ty2[tid] = y2;
        s_lab[tid] = t[4];
        s_area[tid] = (x2 - x1) * (y2 - y1);
        unsigned revp = (unsigned)(g_best[b * NOBJ + tid] & 0xFFFFFFFFull);
        s_bpi[tid] = (int)(0xFFFFFFFFu - revp);
    }
    __syncthreads();

    int n_pos = 0;
    float lloss = 0.f;
    const int p0 = chunk * CHUNK, p1 = p0 + CHUNK;
    for (int p = p0 + tid; p < p1; p += 256) {
        float4 pr = ((const float4*)priors)[p];
        float px1 = pr.x - pr.z * 0.5f, py1 = pr.y - pr.w * 0.5f;
        float px2 = pr.x + pr.z * 0.5f, py2 = pr.y + pr.w * 0.5f;
        float pa = (px2 - px1) * (py2 - py1);
        float bt_ov = -1.f;
        int bt_idx = 0;
        #pragma unroll
        for (int t = 0; t < NOBJ; ++t) {
            float ix1 = fmaxf(s_tx1[t], px1), iy1 = fmaxf(s_ty1[t], py1);
            float ix2 = fminf(s_tx2[t], px2), iy2 = fminf(s_ty2[t], py2);
            float iw = fmaxf(ix2 - ix1, 0.f), ih = fmaxf(iy2 - iy1, 0.f);
            float inter = iw * ih;
            float iou = inter / (s_area[t] + pa - inter);
            if (iou > bt_ov) { bt_ov = iou; bt_idx = t; }  // strict >: first-max
        }
        #pragma unroll
        for (int i = 0; i < NOBJ; ++i)           // last-wins scatter override
            if (s_bpi[i] == p) { bt_idx = i; bt_ov = 2.0f; }

        int c = (bt_ov < THRESH) ? 0 : ((int)s_lab[bt_idx] + 1);
        conf_t[(size_t)b * PP + p] = (unsigned char)c;

        if (c > 0) {
            n_pos++;
            float mx1 = s_tx1[bt_idx], my1 = s_ty1[bt_idx];
            float mx2 = s_tx2[bt_idx], my2 = s_ty2[bt_idx];
            float gcx = ((mx1 + mx2) * 0.5f - pr.x) / (0.1f * pr.z);
            float gcy = ((my1 + my2) * 0.5f - pr.y) / (0.1f * pr.w);
            float gw = logf((mx2 - mx1) / pr.z) / 0.2f;
            float gh = logf((my2 - my1) / pr.w) / 0.2f;
            float4 ld = ((const float4*)loc_data)[(size_t)b * PP + p];
            lloss += smooth_l1(ld.x - gcx) + smooth_l1(ld.y - gcy) +
                     smooth_l1(ld.z - gw) + smooth_l1(ld.w - gh);
        }
    }

    for (int o = 32; o > 0; o >>= 1) {
        n_pos += __shfl_down(n_pos, o);
        lloss += __shfl_down(lloss, o);
    }
    __shared__ int s_np[4];
    __shared__ float s_ll[4];
    int wave = tid >> 6, lane = tid & 63;
    if (lane == 0) { s_np[wave] = n_pos; s_ll[wave] = lloss; }
    __syncthreads();
    if (tid == 0) {
        atomicAdd(&num_pos[b], s_np[0] + s_np[1] + s_np[2] + s_np[3]);
        atomicAdd(&accum[0], (double)(s_ll[0] + s_ll[1] + s_ll[2] + s_ll[3]));
    }
}

// ---------- Kernel 2: conf loss, one wave per (b,p) row (coalesced) ----------
__global__ __launch_bounds__(256) void k_conf(
    const float* __restrict__ conf_data, const unsigned char* __restrict__ conf_t,
    float* __restrict__ lcm, double* __restrict__ accum)
{
    const int lane = threadIdx.x & 63;
    const int wid = (blockIdx.x * 256 + threadIdx.x) >> 6;
    const int nw = (gridDim.x * 256) >> 6;

    float posl = 0.f;
    for (int row = wid; row < BB * PP; row += nw) {
        const float* r = conf_data + (size_t)row * NC;
        float v0 = r[lane];
        bool has2 = lane < (NC - 64);               // 17 tail elements
        float v1 = has2 ? r[64 + lane] : -1e30f;

        float m = fmaxf(v0, v1);
        for (int o = 32; o > 0; o >>= 1) m = fmaxf(m, __shfl_xor(m, o));
        float s = __expf(v0 - m) + (has2 ? __expf(v1 - m) : 0.f);
        for (int o = 32; o > 0; o >>= 1) s += __shfl_xor(s, o);
        float lse = m + __logf(s);

        int c = (int)conf_t[row];
        float vc = (c < 64) ? __shfl(v0, c) : __shfl(v1, c - 64);
        float lc = lse - vc;
        bool pos = c > 0;
        if (lane == 0) {
            lcm[row] = pos ? 0.f : lc;
            if (pos) posl += lc;
        }
    }
    // block reduce (lane0 of each wave holds a partial)
    __shared__ float s_w[4];
    int wave = threadIdx.x >> 6;
    if (lane == 0) s_w[wave] = posl;
    __syncthreads();
    if (threadIdx.x == 0)
        atomicAdd(&accum[1], (double)(s_w[0] + s_w[1] + s_w[2] + s_w[3]));
}

// ---------- Kernel 3: per-batch top-k sum (radix threshold search) ----------
__global__ __launch_bounds__(1024) void k_topk(
    const float* __restrict__ lcm, const int* __restrict__ num_pos,
    double* __restrict__ accum)
{
    __shared__ unsigned s_keys[PP];
    __shared__ int s_cnt[32];
    const int b = blockIdx.x, tid = threadIdx.x;
    for (int i = tid; i < PP; i += 1024)
        s_keys[i] = __float_as_uint(lcm[(size_t)b * PP + i]);
    if (tid < 32) s_cnt[tid] = 0;
    int k = NEGPOS * num_pos[b];
    if (k > PP - 1) k = PP - 1;
    __syncthreads();

    unsigned T = 0;
    for (int bit = 31; bit >= 0; --bit) {
        unsigned cand = T | (1u << bit);
        int cnt = 0;
        for (int i = tid; i < PP; i += 1024) cnt += (s_keys[i] >= cand) ? 1 : 0;
        for (int o = 32; o > 0; o >>= 1) cnt += __shfl_down(cnt, o);
        if ((tid & 63) == 0) atomicAdd(&s_cnt[bit], cnt);
        __syncthreads();
        if (s_cnt[bit] >= k) T = cand;     // uniform: all read same shared value
    }

    float sum = 0.f;
    int cgt = 0;
    for (int i = tid; i < PP; i += 1024) {
        unsigned kk = s_keys[i];
        if (kk > T) { sum += __uint_as_float(kk); cgt++; }
    }
    for (int o = 32; o > 0; o >>= 1) {
        sum += __shfl_down(sum, o);
        cgt += __shfl_down(cgt, o);
    }
    __shared__ float s_s[16];
    __shared__ int s_c[16];
    int wave = tid >> 6, lane = tid & 63;
    if (lane == 0) { s_s[wave] = sum; s_c[wave] = cgt; }
    __syncthreads();
    if (tid == 0) {
        float tot = 0.f; int ctot = 0;
        for (int w = 0; w < 16; ++w) { tot += s_s[w]; ctot += s_c[w]; }
        float neg = tot + (float)(k - ctot) * __uint_as_float(T);
        atomicAdd(&accum[1], (double)neg);
    }
}

// ---------- Kernel 4: finalize ----------
__global__ __launch_bounds__(64) void k_final(
    const int* __restrict__ num_pos, const double* __restrict__ accum,
    float* __restrict__ out)
{
    int tid = threadIdx.x;
    int n = (tid < BB) ? num_pos[tid] : 0;
    for (int o = 32; o > 0; o >>= 1) n += __shfl_down(n, o);
    if (tid == 0)
        out[0] = (float)((accum[0] + accum[1]) / (double)n);  // ALPHA = 1
}

extern "C" void kernel_launch(void* const* d_in, const int* in_sizes, int n_in,
                              void* d_out, int out_size, void* d_ws, size_t ws_size,
                              hipStream_t stream) {
    const float* loc_data  = (const float*)d_in[0];
    const float* conf_data = (const float*)d_in[1];
    const float* priors    = (const float*)d_in[2];
    const float* targets   = (const float*)d_in[3];

    char* ws = (char*)d_ws;
    // layout: [0,16) double accum[2]; [16,272) int num_pos[64];
    //         [512,8704) u64 g_best[64*16]; [8704, +BB*PP) u8 conf_t;
    //         then float lcm[BB*PP] (offset 567552, 4-aligned)
    double* accum = (double*)ws;
    int* num_pos = (int*)(ws + 16);
    unsigned long long* g_best = (unsigned long long*)(ws + 512);
    unsigned char* conf_t = (unsigned char*)(ws + 8704);
    float* lcm = (float*)(ws + 8704 + (size_t)BB * PP);

    hipMemsetAsync(ws, 0, 8704, stream);

    dim3 mg(NCHUNK, BB);
    k_matchA<<<mg, 256, 0, stream>>>(priors, targets, g_best);
    k_matchB<<<mg, 256, 0, stream>>>(loc_data, priors, targets, g_best,
                                     conf_t, num_pos, accum);

    k_conf<<<4096, 256, 0, stream>>>(conf_data, conf_t, lcm, accum);

    k_topk<<<BB, 1024, 0, stream>>>(lcm, num_pos, accum);

    k_final<<<1, 64, 0, stream>>>(num_pos, accum, (float*)d_out);
}

// Round 3
// 351.058 us; speedup vs baseline: 2.2168x; 1.1230x over previous
//
#include <hip/hip_runtime.h>

#define BB 64
#define PP 8732
#define NOBJ 16
#define NC 81
#define THRESH 0.5f
#define NEGPOS 3
#define NCHUNK 4
#define CHUNK (PP / NCHUNK)   // 2183

__device__ __forceinline__ float smooth_l1(float x) {
    float ax = fabsf(x);
    return (ax < 1.0f) ? 0.5f * x * x : ax - 0.5f;
}

// ---------- Kernel 1A: per-truth best prior (global u64 atomicMax) ----------
__global__ __launch_bounds__(256) void k_matchA(
    const float* __restrict__ priors, const float* __restrict__ targets,
    unsigned long long* __restrict__ g_best)
{
    const int chunk = blockIdx.x;
    const int b = blockIdx.y;
    const int tid = threadIdx.x;

    __shared__ float s_tx1[NOBJ], s_ty1[NOBJ], s_tx2[NOBJ], s_ty2[NOBJ];
    __shared__ float s_area[NOBJ];
    __shared__ unsigned long long s_best[NOBJ];

    if (tid < NOBJ) {
        const float* t = targets + ((size_t)b * NOBJ + tid) * 5;
        float x1 = t[0], y1 = t[1], x2 = t[2], y2 = t[3];
        s_tx1[tid] = x1; s_ty1[tid] = y1; s_tx2[tid] = x2; s_ty2[tid] = y2;
        s_area[tid] = (x2 - x1) * (y2 - y1);
        s_best[tid] = 0ull;
    }
    __syncthreads();

    unsigned long long best[NOBJ];
    #pragma unroll
    for (int t = 0; t < NOBJ; ++t) best[t] = 0ull;

    const int p0 = chunk * CHUNK, p1 = p0 + CHUNK;
    for (int p = p0 + tid; p < p1; p += 256) {
        float4 pr = ((const float4*)priors)[p];
        float px1 = pr.x - pr.z * 0.5f, py1 = pr.y - pr.w * 0.5f;
        float px2 = pr.x + pr.z * 0.5f, py2 = pr.y + pr.w * 0.5f;
        float pa = (px2 - px1) * (py2 - py1);
        unsigned revp = 0xFFFFFFFFu - (unsigned)p;
        #pragma unroll
        for (int t = 0; t < NOBJ; ++t) {
            float ix1 = fmaxf(s_tx1[t], px1), iy1 = fmaxf(s_ty1[t], py1);
            float ix2 = fminf(s_tx2[t], px2), iy2 = fminf(s_ty2[t], py2);
            float iw = fmaxf(ix2 - ix1, 0.f), ih = fmaxf(iy2 - iy1, 0.f);
            float inter = iw * ih;
            float iou = inter / (s_area[t] + pa - inter);
            unsigned long long key =
                ((unsigned long long)__float_as_uint(iou) << 32) | revp;
            if (key > best[t]) best[t] = key;
        }
    }
    #pragma unroll
    for (int t = 0; t < NOBJ; ++t) {
        unsigned long long v = best[t];
        for (int o = 32; o > 0; o >>= 1) {
            unsigned long long w = __shfl_down(v, o);
            if (w > v) v = w;
        }
        if ((tid & 63) == 0) atomicMax(&s_best[t], v);
    }
    __syncthreads();
    if (tid < NOBJ) atomicMax(&g_best[b * NOBJ + tid], s_best[tid]);
}

// ---------- Kernel 1B: per-prior match + loc loss + conf_t ----------
__global__ __launch_bounds__(256) void k_matchB(
    const float* __restrict__ loc_data, const float* __restrict__ priors,
    const float* __restrict__ targets, const unsigned long long* __restrict__ g_best,
    unsigned char* __restrict__ conf_t, int* __restrict__ num_pos,
    double* __restrict__ accum)
{
    const int chunk = blockIdx.x;
    const int b = blockIdx.y;
    const int tid = threadIdx.x;

    __shared__ float s_tx1[NOBJ], s_ty1[NOBJ], s_tx2[NOBJ], s_ty2[NOBJ];
    __shared__ float s_lab[NOBJ], s_area[NOBJ];
    __shared__ int s_bpi[NOBJ];

    if (tid < NOBJ) {
        const float* t = targets + ((size_t)b * NOBJ + tid) * 5;
        float x1 = t[0], y1 = t[1], x2 = t[2], y2 = t[3];
        s_tx1[tid] = x1; s_ty1[tid] = y1; s_tx2[tid] = x2; s_ty2[tid] = y2;
        s_lab[tid] = t[4];
        s_area[tid] = (x2 - x1) * (y2 - y1);
        unsigned revp = (unsigned)(g_best[b * NOBJ + tid] & 0xFFFFFFFFull);
        s_bpi[tid] = (int)(0xFFFFFFFFu - revp);
    }
    __syncthreads();

    int n_pos = 0;
    float lloss = 0.f;
    const int p0 = chunk * CHUNK, p1 = p0 + CHUNK;
    for (int p = p0 + tid; p < p1; p += 256) {
        float4 pr = ((const float4*)priors)[p];
        float px1 = pr.x - pr.z * 0.5f, py1 = pr.y - pr.w * 0.5f;
        float px2 = pr.x + pr.z * 0.5f, py2 = pr.y + pr.w * 0.5f;
        float pa = (px2 - px1) * (py2 - py1);
        float bt_ov = -1.f;
        int bt_idx = 0;
        #pragma unroll
        for (int t = 0; t < NOBJ; ++t) {
            float ix1 = fmaxf(s_tx1[t], px1), iy1 = fmaxf(s_ty1[t], py1);
            float ix2 = fminf(s_tx2[t], px2), iy2 = fminf(s_ty2[t], py2);
            float iw = fmaxf(ix2 - ix1, 0.f), ih = fmaxf(iy2 - iy1, 0.f);
            float inter = iw * ih;
            float iou = inter / (s_area[t] + pa - inter);
            if (iou > bt_ov) { bt_ov = iou; bt_idx = t; }  // strict >: first-max
        }
        #pragma unroll
        for (int i = 0; i < NOBJ; ++i)           // last-wins scatter override
            if (s_bpi[i] == p) { bt_idx = i; bt_ov = 2.0f; }

        int c = (bt_ov < THRESH) ? 0 : ((int)s_lab[bt_idx] + 1);
        conf_t[(size_t)b * PP + p] = (unsigned char)c;

        if (c > 0) {
            n_pos++;
            float mx1 = s_tx1[bt_idx], my1 = s_ty1[bt_idx];
            float mx2 = s_tx2[bt_idx], my2 = s_ty2[bt_idx];
            float gcx = ((mx1 + mx2) * 0.5f - pr.x) / (0.1f * pr.z);
            float gcy = ((my1 + my2) * 0.5f - pr.y) / (0.1f * pr.w);
            float gw = logf((mx2 - mx1) / pr.z) / 0.2f;
            float gh = logf((my2 - my1) / pr.w) / 0.2f;
            float4 ld = ((const float4*)loc_data)[(size_t)b * PP + p];
            lloss += smooth_l1(ld.x - gcx) + smooth_l1(ld.y - gcy) +
                     smooth_l1(ld.z - gw) + smooth_l1(ld.w - gh);
        }
    }

    for (int o = 32; o > 0; o >>= 1) {
        n_pos += __shfl_down(n_pos, o);
        lloss += __shfl_down(lloss, o);
    }
    __shared__ int s_np[4];
    __shared__ float s_ll[4];
    int wave = tid >> 6, lane = tid & 63;
    if (lane == 0) { s_np[wave] = n_pos; s_ll[wave] = lloss; }
    __syncthreads();
    if (tid == 0) {
        atomicAdd(&num_pos[b], s_np[0] + s_np[1] + s_np[2] + s_np[3]);
        atomicAdd(&accum[0], (double)(s_ll[0] + s_ll[1] + s_ll[2] + s_ll[3]));
    }
}

// ---------- Kernel 2: conf loss, LDS-staged, quad-per-row ----------
// 2183 blocks x 256 threads; each block: 256 rows in 4 chunks of 64.
// Stage 64 rows (1296 float4) coalesced into LDS; each row computed by a
// 4-lane quad (segments 21/21/21/18), combined with 2 in-quad shfl_xor.
__global__ __launch_bounds__(256) void k_conf(
    const float* __restrict__ conf_data, const unsigned char* __restrict__ conf_t,
    float* __restrict__ lcm, double* __restrict__ accum)
{
    __shared__ float4 s_buf4[1300];          // 1296 data + 4 pad (r=63,s=3 tail)
    float* s_data = (float*)s_buf4;
    const int tid = threadIdx.x;
    const int r = tid >> 2;                  // row within chunk (0..63)
    const int s = tid & 3;                   // segment (0..3)
    const int seg_start = s * 21;
    const int seg_len = (s == 3) ? 18 : 21;
    const int base_row = blockIdx.x * 256;   // 2183*256 == BB*PP exactly

    if (tid < 4)                             // poison pad once (never re-written)
        s_buf4[1296 + tid] = make_float4(-1e30f, -1e30f, -1e30f, -1e30f);

    float posl = 0.f;
    for (int ch = 0; ch < 4; ++ch) {
        const int row0 = base_row + ch * 64;
        const float4* g4 = (const float4*)conf_data + ((size_t)row0 * NC >> 2);
        __syncthreads();                     // prev chunk fully consumed
        for (int i = tid; i < 1296; i += 256)
            s_buf4[i] = g4[i];
        __syncthreads();

        const float* myrow = s_data + r * NC;
        float m = -1e30f;
        #pragma unroll
        for (int j = 0; j < 21; ++j) {
            float v = myrow[seg_start + j];
            m = fmaxf(m, (j < seg_len) ? v : -1e30f);
        }
        m = fmaxf(m, __shfl_xor(m, 1));
        m = fmaxf(m, __shfl_xor(m, 2));
        float e = 0.f;
        #pragma unroll
        for (int j = 0; j < 21; ++j) {
            float v = myrow[seg_start + j];
            e += (j < seg_len) ? __expf(v - m) : 0.f;
        }
        e += __shfl_xor(e, 1);
        e += __shfl_xor(e, 2);
        if (s == 0) {
            float lse = m + __logf(e);
            int row = row0 + r;
            int c = (int)conf_t[row];
            float lc = lse - myrow[c];
            bool pos = c > 0;
            lcm[row] = pos ? 0.f : lc;
            if (pos) posl += lc;
        }
    }
    // block reduce posl (only s==0 lanes nonzero)
    for (int o = 32; o > 0; o >>= 1) posl += __shfl_down(posl, o);
    __shared__ float s_w[4];
    if ((tid & 63) == 0) s_w[tid >> 6] = posl;
    __syncthreads();
    if (tid == 0)
        atomicAdd(&accum[1], (double)(s_w[0] + s_w[1] + s_w[2] + s_w[3]));
}

// ---------- Kernel 3: per-batch top-k sum (radix threshold search) ----------
__global__ __launch_bounds__(1024) void k_topk(
    const float* __restrict__ lcm, const int* __restrict__ num_pos,
    double* __restrict__ accum)
{
    __shared__ unsigned s_keys[PP];
    __shared__ int s_cnt[32];
    const int b = blockIdx.x, tid = threadIdx.x;
    for (int i = tid; i < PP; i += 1024)
        s_keys[i] = __float_as_uint(lcm[(size_t)b * PP + i]);
    if (tid < 32) s_cnt[tid] = 0;
    int k = NEGPOS * num_pos[b];
    if (k > PP - 1) k = PP - 1;
    __syncthreads();

    unsigned T = 0;
    for (int bit = 30; bit >= 0; --bit) {   // losses >= 0 -> sign bit always 0
        unsigned cand = T | (1u << bit);
        int cnt = 0;
        for (int i = tid; i < PP; i += 1024) cnt += (s_keys[i] >= cand) ? 1 : 0;
        for (int o = 32; o > 0; o >>= 1) cnt += __shfl_down(cnt, o);
        if ((tid & 63) == 0) atomicAdd(&s_cnt[bit], cnt);
        __syncthreads();
        if (s_cnt[bit] >= k) T = cand;     // uniform: all read same shared value
    }

    float sum = 0.f;
    int cgt = 0;
    for (int i = tid; i < PP; i += 1024) {
        unsigned kk = s_keys[i];
        if (kk > T) { sum += __uint_as_float(kk); cgt++; }
    }
    for (int o = 32; o > 0; o >>= 1) {
        sum += __shfl_down(sum, o);
        cgt += __shfl_down(cgt, o);
    }
    __shared__ float s_s[16];
    __shared__ int s_c[16];
    int wave = tid >> 6, lane = tid & 63;
    if (lane == 0) { s_s[wave] = sum; s_c[wave] = cgt; }
    __syncthreads();
    if (tid == 0) {
        float tot = 0.f; int ctot = 0;
        for (int w = 0; w < 16; ++w) { tot += s_s[w]; ctot += s_c[w]; }
        float neg = tot + (float)(k - ctot) * __uint_as_float(T);
        atomicAdd(&accum[1], (double)neg);
    }
}

// ---------- Kernel 4: finalize ----------
__global__ __launch_bounds__(64) void k_final(
    const int* __restrict__ num_pos, const double* __restrict__ accum,
    float* __restrict__ out)
{
    int tid = threadIdx.x;
    int n = (tid < BB) ? num_pos[tid] : 0;
    for (int o = 32; o > 0; o >>= 1) n += __shfl_down(n, o);
    if (tid == 0)
        out[0] = (float)((accum[0] + accum[1]) / (double)n);  // ALPHA = 1
}

extern "C" void kernel_launch(void* const* d_in, const int* in_sizes, int n_in,
                              void* d_out, int out_size, void* d_ws, size_t ws_size,
                              hipStream_t stream) {
    const float* loc_data  = (const float*)d_in[0];
    const float* conf_data = (const float*)d_in[1];
    const float* priors    = (const float*)d_in[2];
    const float* targets   = (const float*)d_in[3];

    char* ws = (char*)d_ws;
    // layout: [0,16) double accum[2]; [16,272) int num_pos[64];
    //         [512,8704) u64 g_best[64*16]; [8704, +BB*PP) u8 conf_t;
    //         then float lcm[BB*PP] (offset 567552, 4-aligned)
    double* accum = (double*)ws;
    int* num_pos = (int*)(ws + 16);
    unsigned long long* g_best = (unsigned long long*)(ws + 512);
    unsigned char* conf_t = (unsigned char*)(ws + 8704);
    float* lcm = (float*)(ws + 8704 + (size_t)BB * PP);

    hipMemsetAsync(ws, 0, 8704, stream);

    dim3 mg(NCHUNK, BB);
    k_matchA<<<mg, 256, 0, stream>>>(priors, targets, g_best);
    k_matchB<<<mg, 256, 0, stream>>>(loc_data, priors, targets, g_best,
                                     conf_t, num_pos, accum);

    k_conf<<<(BB * PP) / 256, 256, 0, stream>>>(conf_data, conf_t, lcm, accum);

    k_topk<<<BB, 1024, 0, stream>>>(lcm, num_pos, accum);

    k_final<<<1, 64, 0, stream>>>(num_pos, accum, (float*)d_out);
}

// Round 4
// 333.588 us; speedup vs baseline: 2.3328x; 1.0524x over previous
//
#include <hip/hip_runtime.h>

#define BB 64
#define PP 8732
#define NOBJ 16
#define NC 81
#define THRESH 0.5f
#define NEGPOS 3
#define NCHUNK 4
#define CHUNK (PP / NCHUNK)   // 2183

#define TK_THREADS 512
#define TK_KEYS 18            // 17*512 = 8704; threads 0..27 hold an 18th key

__device__ __forceinline__ float smooth_l1(float x) {
    float ax = fabsf(x);
    return (ax < 1.0f) ? 0.5f * x * x : ax - 0.5f;
}

// ---------- Kernel 1A: per-truth best prior (global u64 atomicMax) ----------
__global__ __launch_bounds__(256) void k_matchA(
    const float* __restrict__ priors, const float* __restrict__ targets,
    unsigned long long* __restrict__ g_best)
{
    const int chunk = blockIdx.x;
    const int b = blockIdx.y;
    const int tid = threadIdx.x;

    __shared__ float s_tx1[NOBJ], s_ty1[NOBJ], s_tx2[NOBJ], s_ty2[NOBJ];
    __shared__ float s_area[NOBJ];
    __shared__ unsigned long long s_best[NOBJ];

    if (tid < NOBJ) {
        const float* t = targets + ((size_t)b * NOBJ + tid) * 5;
        float x1 = t[0], y1 = t[1], x2 = t[2], y2 = t[3];
        s_tx1[tid] = x1; s_ty1[tid] = y1; s_tx2[tid] = x2; s_ty2[tid] = y2;
        s_area[tid] = (x2 - x1) * (y2 - y1);
        s_best[tid] = 0ull;
    }
    __syncthreads();

    unsigned long long best[NOBJ];
    #pragma unroll
    for (int t = 0; t < NOBJ; ++t) best[t] = 0ull;

    const int p0 = chunk * CHUNK, p1 = p0 + CHUNK;
    for (int p = p0 + tid; p < p1; p += 256) {
        float4 pr = ((const float4*)priors)[p];
        float px1 = pr.x - pr.z * 0.5f, py1 = pr.y - pr.w * 0.5f;
        float px2 = pr.x + pr.z * 0.5f, py2 = pr.y + pr.w * 0.5f;
        float pa = (px2 - px1) * (py2 - py1);
        unsigned revp = 0xFFFFFFFFu - (unsigned)p;
        #pragma unroll
        for (int t = 0; t < NOBJ; ++t) {
            float ix1 = fmaxf(s_tx1[t], px1), iy1 = fmaxf(s_ty1[t], py1);
            float ix2 = fminf(s_tx2[t], px2), iy2 = fminf(s_ty2[t], py2);
            float iw = fmaxf(ix2 - ix1, 0.f), ih = fmaxf(iy2 - iy1, 0.f);
            float inter = iw * ih;
            float iou = inter / (s_area[t] + pa - inter);
            unsigned long long key =
                ((unsigned long long)__float_as_uint(iou) << 32) | revp;
            if (key > best[t]) best[t] = key;
        }
    }
    #pragma unroll
    for (int t = 0; t < NOBJ; ++t) {
        unsigned long long v = best[t];
        for (int o = 32; o > 0; o >>= 1) {
            unsigned long long w = __shfl_down(v, o);
            if (w > v) v = w;
        }
        if ((tid & 63) == 0) atomicMax(&s_best[t], v);
    }
    __syncthreads();
    if (tid < NOBJ) atomicMax(&g_best[b * NOBJ + tid], s_best[tid]);
}

// ---------- Kernel 1B: per-prior match + loc loss + conf_t ----------
__global__ __launch_bounds__(256) void k_matchB(
    const float* __restrict__ loc_data, const float* __restrict__ priors,
    const float* __restrict__ targets, const unsigned long long* __restrict__ g_best,
    unsigned char* __restrict__ conf_t, int* __restrict__ num_pos,
    double* __restrict__ accum)
{
    const int chunk = blockIdx.x;
    const int b = blockIdx.y;
    const int tid = threadIdx.x;

    __shared__ float s_tx1[NOBJ], s_ty1[NOBJ], s_tx2[NOBJ], s_ty2[NOBJ];
    __shared__ float s_lab[NOBJ], s_area[NOBJ];
    __shared__ int s_bpi[NOBJ];

    if (tid < NOBJ) {
        const float* t = targets + ((size_t)b * NOBJ + tid) * 5;
        float x1 = t[0], y1 = t[1], x2 = t[2], y2 = t[3];
        s_tx1[tid] = x1; s_ty1[tid] = y1; s_tx2[tid] = x2; s_ty2[tid] = y2;
        s_lab[tid] = t[4];
        s_area[tid] = (x2 - x1) * (y2 - y1);
        unsigned revp = (unsigned)(g_best[b * NOBJ + tid] & 0xFFFFFFFFull);
        s_bpi[tid] = (int)(0xFFFFFFFFu - revp);
    }
    __syncthreads();

    int n_pos = 0;
    float lloss = 0.f;
    const int p0 = chunk * CHUNK, p1 = p0 + CHUNK;
    for (int p = p0 + tid; p < p1; p += 256) {
        float4 pr = ((const float4*)priors)[p];
        float px1 = pr.x - pr.z * 0.5f, py1 = pr.y - pr.w * 0.5f;
        float px2 = pr.x + pr.z * 0.5f, py2 = pr.y + pr.w * 0.5f;
        float pa = (px2 - px1) * (py2 - py1);
        float bt_ov = -1.f;
        int bt_idx = 0;
        #pragma unroll
        for (int t = 0; t < NOBJ; ++t) {
            float ix1 = fmaxf(s_tx1[t], px1), iy1 = fmaxf(s_ty1[t], py1);
            float ix2 = fminf(s_tx2[t], px2), iy2 = fminf(s_ty2[t], py2);
            float iw = fmaxf(ix2 - ix1, 0.f), ih = fmaxf(iy2 - iy1, 0.f);
            float inter = iw * ih;
            float iou = inter / (s_area[t] + pa - inter);
            if (iou > bt_ov) { bt_ov = iou; bt_idx = t; }  // strict >: first-max
        }
        #pragma unroll
        for (int i = 0; i < NOBJ; ++i)           // last-wins scatter override
            if (s_bpi[i] == p) { bt_idx = i; bt_ov = 2.0f; }

        int c = (bt_ov < THRESH) ? 0 : ((int)s_lab[bt_idx] + 1);
        conf_t[(size_t)b * PP + p] = (unsigned char)c;

        if (c > 0) {
            n_pos++;
            float mx1 = s_tx1[bt_idx], my1 = s_ty1[bt_idx];
            float mx2 = s_tx2[bt_idx], my2 = s_ty2[bt_idx];
            float gcx = ((mx1 + mx2) * 0.5f - pr.x) / (0.1f * pr.z);
            float gcy = ((my1 + my2) * 0.5f - pr.y) / (0.1f * pr.w);
            float gw = logf((mx2 - mx1) / pr.z) / 0.2f;
            float gh = logf((my2 - my1) / pr.w) / 0.2f;
            float4 ld = ((const float4*)loc_data)[(size_t)b * PP + p];
            lloss += smooth_l1(ld.x - gcx) + smooth_l1(ld.y - gcy) +
                     smooth_l1(ld.z - gw) + smooth_l1(ld.w - gh);
        }
    }

    for (int o = 32; o > 0; o >>= 1) {
        n_pos += __shfl_down(n_pos, o);
        lloss += __shfl_down(lloss, o);
    }
    __shared__ int s_np[4];
    __shared__ float s_ll[4];
    int wave = tid >> 6, lane = tid & 63;
    if (lane == 0) { s_np[wave] = n_pos; s_ll[wave] = lloss; }
    __syncthreads();
    if (tid == 0) {
        atomicAdd(&num_pos[b], s_np[0] + s_np[1] + s_np[2] + s_np[3]);
        atomicAdd(&accum[0], (double)(s_ll[0] + s_ll[1] + s_ll[2] + s_ll[3]));
    }
}

// ---------- Kernel 2: conf loss, LDS-staged, quad-per-row ----------
__global__ __launch_bounds__(256) void k_conf(
    const float* __restrict__ conf_data, const unsigned char* __restrict__ conf_t,
    float* __restrict__ lcm, double* __restrict__ accum)
{
    __shared__ float4 s_buf4[1300];          // 1296 data + 4 pad (r=63,s=3 tail)
    float* s_data = (float*)s_buf4;
    const int tid = threadIdx.x;
    const int r = tid >> 2;                  // row within chunk (0..63)
    const int s = tid & 3;                   // segment (0..3)
    const int seg_start = s * 21;
    const int seg_len = (s == 3) ? 18 : 21;
    const int base_row = blockIdx.x * 256;   // 2183*256 == BB*PP exactly

    if (tid < 4)                             // poison pad once (never re-written)
        s_buf4[1296 + tid] = make_float4(-1e30f, -1e30f, -1e30f, -1e30f);

    float posl = 0.f;
    for (int ch = 0; ch < 4; ++ch) {
        const int row0 = base_row + ch * 64;
        const float4* g4 = (const float4*)conf_data + ((size_t)row0 * NC >> 2);
        __syncthreads();                     // prev chunk fully consumed
        for (int i = tid; i < 1296; i += 256)
            s_buf4[i] = g4[i];
        __syncthreads();

        const float* myrow = s_data + r * NC;
        float m = -1e30f;
        #pragma unroll
        for (int j = 0; j < 21; ++j) {
            float v = myrow[seg_start + j];
            m = fmaxf(m, (j < seg_len) ? v : -1e30f);
        }
        m = fmaxf(m, __shfl_xor(m, 1));
        m = fmaxf(m, __shfl_xor(m, 2));
        float e = 0.f;
        #pragma unroll
        for (int j = 0; j < 21; ++j) {
            float v = myrow[seg_start + j];
            e += (j < seg_len) ? __expf(v - m) : 0.f;
        }
        e += __shfl_xor(e, 1);
        e += __shfl_xor(e, 2);
        if (s == 0) {
            float lse = m + __logf(e);
            int row = row0 + r;
            int c = (int)conf_t[row];
            float lc = lse - myrow[c];
            bool pos = c > 0;
            lcm[row] = pos ? 0.f : lc;
            if (pos) posl += lc;
        }
    }
    for (int o = 32; o > 0; o >>= 1) posl += __shfl_down(posl, o);
    __shared__ float s_w[4];
    if ((tid & 63) == 0) s_w[tid >> 6] = posl;
    __syncthreads();
    if (tid == 0)
        atomicAdd(&accum[1], (double)(s_w[0] + s_w[1] + s_w[2] + s_w[3]));
}

// ---------- Kernel 3: per-batch top-k sum, register-resident radix scan ----
// 64 blocks x 512 threads. Keys loop-invariant -> held in 18 VGPRs/thread.
// Per bit: 18 v_cmp + ballot/popc (uniform, no shfl chain) + 1 LDS atomic
// per wave + one 8-wave barrier. 31 bits total.
__global__ __launch_bounds__(TK_THREADS) void k_topk(
    const float* __restrict__ lcm, const int* __restrict__ num_pos,
    double* __restrict__ accum)
{
    const int b = blockIdx.x, tid = threadIdx.x;
    unsigned key[TK_KEYS];
    #pragma unroll
    for (int j = 0; j < TK_KEYS; ++j) {
        int i = tid + j * TK_THREADS;
        key[j] = (i < PP) ? __float_as_uint(lcm[(size_t)b * PP + i]) : 0u;
    }
    __shared__ int s_cnt[32];
    if (tid < 32) s_cnt[tid] = 0;
    int k = NEGPOS * num_pos[b];
    if (k > PP - 1) k = PP - 1;
    __syncthreads();

    unsigned T = 0;
    for (int bit = 30; bit >= 0; --bit) {   // losses >= 0 -> sign bit always 0
        unsigned cand = T | (1u << bit);
        int cnt = 0;
        #pragma unroll
        for (int j = 0; j < TK_KEYS; ++j)
            cnt += (int)__popcll(__ballot(key[j] >= cand));
        if ((tid & 63) == 0) atomicAdd(&s_cnt[bit], cnt);
        __syncthreads();
        if (s_cnt[bit] >= k) T = cand;      // uniform across block
    }

    // sum of top-k = sum(keys > T) + (k - count(keys > T)) * T
    float sum = 0.f;
    int cgt = 0;
    #pragma unroll
    for (int j = 0; j < TK_KEYS; ++j) {
        if (key[j] > T) { sum += __uint_as_float(key[j]); cgt++; }
    }
    for (int o = 32; o > 0; o >>= 1) {
        sum += __shfl_down(sum, o);
        cgt += __shfl_down(cgt, o);
    }
    __shared__ float s_s[8];
    __shared__ int s_c[8];
    if ((tid & 63) == 0) { s_s[tid >> 6] = sum; s_c[tid >> 6] = cgt; }
    __syncthreads();
    if (tid == 0) {
        float tot = 0.f; int ctot = 0;
        for (int w = 0; w < 8; ++w) { tot += s_s[w]; ctot += s_c[w]; }
        float neg = tot + (float)(k - ctot) * __uint_as_float(T);
        atomicAdd(&accum[1], (double)neg);
    }
}

// ---------- Kernel 4: finalize ----------
__global__ __launch_bounds__(64) void k_final(
    const int* __restrict__ num_pos, const double* __restrict__ accum,
    float* __restrict__ out)
{
    int tid = threadIdx.x;
    int n = (tid < BB) ? num_pos[tid] : 0;
    for (int o = 32; o > 0; o >>= 1) n += __shfl_down(n, o);
    if (tid == 0)
        out[0] = (float)((accum[0] + accum[1]) / (double)n);  // ALPHA = 1
}

extern "C" void kernel_launch(void* const* d_in, const int* in_sizes, int n_in,
                              void* d_out, int out_size, void* d_ws, size_t ws_size,
                              hipStream_t stream) {
    const float* loc_data  = (const float*)d_in[0];
    const float* conf_data = (const float*)d_in[1];
    const float* priors    = (const float*)d_in[2];
    const float* targets   = (const float*)d_in[3];

    char* ws = (char*)d_ws;
    // layout: [0,16) double accum[2]; [16,272) int num_pos[64];
    //         [512,8704) u64 g_best[64*16]; [8704, +BB*PP) u8 conf_t;
    //         then float lcm[BB*PP]
    double* accum = (double*)ws;
    int* num_pos = (int*)(ws + 16);
    unsigned long long* g_best = (unsigned long long*)(ws + 512);
    unsigned char* conf_t = (unsigned char*)(ws + 8704);
    float* lcm = (float*)(ws + 8704 + (size_t)BB * PP);

    hipMemsetAsync(ws, 0, 8704, stream);

    dim3 mg(NCHUNK, BB);
    k_matchA<<<mg, 256, 0, stream>>>(priors, targets, g_best);
    k_matchB<<<mg, 256, 0, stream>>>(loc_data, priors, targets, g_best,
                                     conf_t, num_pos, accum);

    k_conf<<<(BB * PP) / 256, 256, 0, stream>>>(conf_data, conf_t, lcm, accum);

    k_topk<<<BB, TK_THREADS, 0, stream>>>(lcm, num_pos, accum);

    k_final<<<1, 64, 0, stream>>>(num_pos, accum, (float*)d_out);
}

// Round 5
// 327.315 us; speedup vs baseline: 2.3776x; 1.0192x over previous
//
#include <hip/hip_runtime.h>

#define BB 64
#define PP 8732
#define NOBJ 16
#define NC 81
#define THRESH 0.5f
#define NEGPOS 3
#define NCHUNK 4
#define CHUNK (PP / NCHUNK)   // 2183

#define TK_THREADS 512
#define TK_KEYS 18            // 17*512 = 8704; threads 0..27 hold an 18th key

__device__ __forceinline__ float smooth_l1(float x) {
    float ax = fabsf(x);
    return (ax < 1.0f) ? 0.5f * x * x : ax - 0.5f;
}

// ---------- Kernel 1A: per-truth best prior (global u64 atomicMax) ----------
__global__ __launch_bounds__(256) void k_matchA(
    const float* __restrict__ priors, const float* __restrict__ targets,
    unsigned long long* __restrict__ g_best)
{
    const int chunk = blockIdx.x;
    const int b = blockIdx.y;
    const int tid = threadIdx.x;

    __shared__ float s_tx1[NOBJ], s_ty1[NOBJ], s_tx2[NOBJ], s_ty2[NOBJ];
    __shared__ float s_area[NOBJ];
    __shared__ unsigned long long s_best[NOBJ];

    if (tid < NOBJ) {
        const float* t = targets + ((size_t)b * NOBJ + tid) * 5;
        float x1 = t[0], y1 = t[1], x2 = t[2], y2 = t[3];
        s_tx1[tid] = x1; s_ty1[tid] = y1; s_tx2[tid] = x2; s_ty2[tid] = y2;
        s_area[tid] = (x2 - x1) * (y2 - y1);
        s_best[tid] = 0ull;
    }
    __syncthreads();

    unsigned long long best[NOBJ];
    #pragma unroll
    for (int t = 0; t < NOBJ; ++t) best[t] = 0ull;

    const int p0 = chunk * CHUNK, p1 = p0 + CHUNK;
    for (int p = p0 + tid; p < p1; p += 256) {
        float4 pr = ((const float4*)priors)[p];
        float px1 = pr.x - pr.z * 0.5f, py1 = pr.y - pr.w * 0.5f;
        float px2 = pr.x + pr.z * 0.5f, py2 = pr.y + pr.w * 0.5f;
        float pa = (px2 - px1) * (py2 - py1);
        unsigned revp = 0xFFFFFFFFu - (unsigned)p;
        #pragma unroll
        for (int t = 0; t < NOBJ; ++t) {
            float ix1 = fmaxf(s_tx1[t], px1), iy1 = fmaxf(s_ty1[t], py1);
            float ix2 = fminf(s_tx2[t], px2), iy2 = fminf(s_ty2[t], py2);
            float iw = fmaxf(ix2 - ix1, 0.f), ih = fmaxf(iy2 - iy1, 0.f);
            float inter = iw * ih;
            float iou = inter / (s_area[t] + pa - inter);
            unsigned long long key =
                ((unsigned long long)__float_as_uint(iou) << 32) | revp;
            if (key > best[t]) best[t] = key;
        }
    }
    #pragma unroll
    for (int t = 0; t < NOBJ; ++t) {
        unsigned long long v = best[t];
        for (int o = 32; o > 0; o >>= 1) {
            unsigned long long w = __shfl_down(v, o);
            if (w > v) v = w;
        }
        if ((tid & 63) == 0) atomicMax(&s_best[t], v);
    }
    __syncthreads();
    if (tid < NOBJ) atomicMax(&g_best[b * NOBJ + tid], s_best[tid]);
}

// ---------- Kernel 1B: per-prior match + loc loss + conf_t ----------
__global__ __launch_bounds__(256) void k_matchB(
    const float* __restrict__ loc_data, const float* __restrict__ priors,
    const float* __restrict__ targets, const unsigned long long* __restrict__ g_best,
    unsigned char* __restrict__ conf_t, int* __restrict__ num_pos,
    double* __restrict__ accum)
{
    const int chunk = blockIdx.x;
    const int b = blockIdx.y;
    const int tid = threadIdx.x;

    __shared__ float s_tx1[NOBJ], s_ty1[NOBJ], s_tx2[NOBJ], s_ty2[NOBJ];
    __shared__ float s_lab[NOBJ], s_area[NOBJ];
    __shared__ int s_bpi[NOBJ];

    if (tid < NOBJ) {
        const float* t = targets + ((size_t)b * NOBJ + tid) * 5;
        float x1 = t[0], y1 = t[1], x2 = t[2], y2 = t[3];
        s_tx1[tid] = x1; s_ty1[tid] = y1; s_tx2[tid] = x2; s_ty2[tid] = y2;
        s_lab[tid] = t[4];
        s_area[tid] = (x2 - x1) * (y2 - y1);
        unsigned revp = (unsigned)(g_best[b * NOBJ + tid] & 0xFFFFFFFFull);
        s_bpi[tid] = (int)(0xFFFFFFFFu - revp);
    }
    __syncthreads();

    int n_pos = 0;
    float lloss = 0.f;
    const int p0 = chunk * CHUNK, p1 = p0 + CHUNK;
    for (int p = p0 + tid; p < p1; p += 256) {
        float4 pr = ((const float4*)priors)[p];
        float px1 = pr.x - pr.z * 0.5f, py1 = pr.y - pr.w * 0.5f;
        float px2 = pr.x + pr.z * 0.5f, py2 = pr.y + pr.w * 0.5f;
        float pa = (px2 - px1) * (py2 - py1);
        float bt_ov = -1.f;
        int bt_idx = 0;
        #pragma unroll
        for (int t = 0; t < NOBJ; ++t) {
            float ix1 = fmaxf(s_tx1[t], px1), iy1 = fmaxf(s_ty1[t], py1);
            float ix2 = fminf(s_tx2[t], px2), iy2 = fminf(s_ty2[t], py2);
            float iw = fmaxf(ix2 - ix1, 0.f), ih = fmaxf(iy2 - iy1, 0.f);
            float inter = iw * ih;
            float iou = inter / (s_area[t] + pa - inter);
            if (iou > bt_ov) { bt_ov = iou; bt_idx = t; }  // strict >: first-max
        }
        #pragma unroll
        for (int i = 0; i < NOBJ; ++i)           // last-wins scatter override
            if (s_bpi[i] == p) { bt_idx = i; bt_ov = 2.0f; }

        int c = (bt_ov < THRESH) ? 0 : ((int)s_lab[bt_idx] + 1);
        conf_t[(size_t)b * PP + p] = (unsigned char)c;

        if (c > 0) {
            n_pos++;
            float mx1 = s_tx1[bt_idx], my1 = s_ty1[bt_idx];
            float mx2 = s_tx2[bt_idx], my2 = s_ty2[bt_idx];
            float gcx = ((mx1 + mx2) * 0.5f - pr.x) / (0.1f * pr.z);
            float gcy = ((my1 + my2) * 0.5f - pr.y) / (0.1f * pr.w);
            float gw = logf((mx2 - mx1) / pr.z) / 0.2f;
            float gh = logf((my2 - my1) / pr.w) / 0.2f;
            float4 ld = ((const float4*)loc_data)[(size_t)b * PP + p];
            lloss += smooth_l1(ld.x - gcx) + smooth_l1(ld.y - gcy) +
                     smooth_l1(ld.z - gw) + smooth_l1(ld.w - gh);
        }
    }

    for (int o = 32; o > 0; o >>= 1) {
        n_pos += __shfl_down(n_pos, o);
        lloss += __shfl_down(lloss, o);
    }
    __shared__ int s_np[4];
    __shared__ float s_ll[4];
    int wave = tid >> 6, lane = tid & 63;
    if (lane == 0) { s_np[wave] = n_pos; s_ll[wave] = lloss; }
    __syncthreads();
    if (tid == 0) {
        atomicAdd(&num_pos[b], s_np[0] + s_np[1] + s_np[2] + s_np[3]);
        atomicAdd(&accum[0], (double)(s_ll[0] + s_ll[1] + s_ll[2] + s_ll[3]));
    }
}

// ---------- Kernel 2: conf loss, double-buffered LDS, octet-per-row ----------
// 2183 blocks x 256 threads; 256 rows/block in 8 half-chunks of 32 rows.
// Pipeline per half-chunk: ds_write regs -> buf[h&1]; issue next global loads
// into regs; ONE barrier; compute (each element LDS-read once into registers).
__global__ __launch_bounds__(256) void k_conf(
    const float* __restrict__ conf_data, const unsigned char* __restrict__ conf_t,
    float* __restrict__ lcm, double* __restrict__ accum)
{
    __shared__ float4 s_buf4[2][648];        // 2 x 32 rows x 81 floats
    const int tid = threadIdx.x;
    const int r = tid >> 3;                  // row in half-chunk (0..31)
    const int s = tid & 7;                   // octet segment (0..7)
    const int seg_start = s * 10;
    const int seg_len = (s == 7) ? 11 : 10;  // 7*10 + 11 = 81
    const int base_row = blockIdx.x * 256;   // 2183*256 == BB*PP exactly
    const float4* g4base = (const float4*)conf_data;

    // initial loads for half-chunk 0 into regs
    float4 t0, t1, t2;
    {
        const float4* g4 = g4base + (size_t)base_row * NC / 4;
        t0 = g4[tid]; t1 = g4[tid + 256];
        if (tid < 136) t2 = g4[tid + 512];
    }

    float posl = 0.f;
    for (int h = 0; h < 8; ++h) {
        float4* buf = s_buf4[h & 1];
        buf[tid] = t0; buf[tid + 256] = t1;
        if (tid < 136) buf[tid + 512] = t2;
        if (h + 1 < 8) {                     // issue next loads (latency hidden)
            const float4* g4 = g4base + (size_t)(base_row + (h + 1) * 32) * NC / 4;
            t0 = g4[tid]; t1 = g4[tid + 256];
            if (tid < 136) t2 = g4[tid + 512];
        }
        __syncthreads();                     // single barrier per half-chunk

        const float* myrow = (const float*)buf + r * NC;
        float v[11];
        #pragma unroll
        for (int j = 0; j < 11; ++j) v[j] = myrow[seg_start + j];

        float m = -1e30f;
        #pragma unroll
        for (int j = 0; j < 11; ++j) m = fmaxf(m, (j < seg_len) ? v[j] : -1e30f);
        m = fmaxf(m, __shfl_xor(m, 1));
        m = fmaxf(m, __shfl_xor(m, 2));
        m = fmaxf(m, __shfl_xor(m, 4));
        float e = 0.f;
        #pragma unroll
        for (int j = 0; j < 11; ++j) e += (j < seg_len) ? __expf(v[j] - m) : 0.f;
        e += __shfl_xor(e, 1);
        e += __shfl_xor(e, 2);
        e += __shfl_xor(e, 4);

        if (s == 0) {
            int row = base_row + h * 32 + r;
            int c = (int)conf_t[row];
            float lse = m + __logf(e);
            float lc = lse - myrow[c];
            bool pos = c > 0;
            lcm[row] = pos ? 0.f : lc;
            if (pos) posl += lc;
        }
    }
    for (int o = 32; o > 0; o >>= 1) posl += __shfl_down(posl, o);
    __shared__ float s_w[4];
    if ((tid & 63) == 0) s_w[tid >> 6] = posl;
    __syncthreads();
    if (tid == 0)
        atomicAdd(&accum[1], (double)(s_w[0] + s_w[1] + s_w[2] + s_w[3]));
}

// ---------- Kernel 3: per-batch top-k sum + fused finalize ----------
__global__ __launch_bounds__(TK_THREADS) void k_topk(
    const float* __restrict__ lcm, const int* __restrict__ num_pos,
    double* __restrict__ accum, int* __restrict__ done_cnt,
    float* __restrict__ out)
{
    const int b = blockIdx.x, tid = threadIdx.x;
    unsigned key[TK_KEYS];
    #pragma unroll
    for (int j = 0; j < TK_KEYS; ++j) {
        int i = tid + j * TK_THREADS;
        key[j] = (i < PP) ? __float_as_uint(lcm[(size_t)b * PP + i]) : 0u;
    }
    __shared__ int s_cnt[32];
    if (tid < 32) s_cnt[tid] = 0;
    int k = NEGPOS * num_pos[b];
    if (k > PP - 1) k = PP - 1;
    __syncthreads();

    unsigned T = 0;
    for (int bit = 30; bit >= 0; --bit) {   // losses >= 0 -> sign bit always 0
        unsigned cand = T | (1u << bit);
        int cnt = 0;
        #pragma unroll
        for (int j = 0; j < TK_KEYS; ++j)
            cnt += (int)__popcll(__ballot(key[j] >= cand));
        if ((tid & 63) == 0) atomicAdd(&s_cnt[bit], cnt);
        __syncthreads();
        if (s_cnt[bit] >= k) T = cand;      // uniform across block
    }

    float sum = 0.f;
    int cgt = 0;
    #pragma unroll
    for (int j = 0; j < TK_KEYS; ++j) {
        if (key[j] > T) { sum += __uint_as_float(key[j]); cgt++; }
    }
    for (int o = 32; o > 0; o >>= 1) {
        sum += __shfl_down(sum, o);
        cgt += __shfl_down(cgt, o);
    }
    __shared__ float s_s[8];
    __shared__ int s_c[8];
    if ((tid & 63) == 0) { s_s[tid >> 6] = sum; s_c[tid >> 6] = cgt; }
    __syncthreads();
    if (tid == 0) {
        float tot = 0.f; int ctot = 0;
        for (int w = 0; w < 8; ++w) { tot += s_s[w]; ctot += s_c[w]; }
        float neg = tot + (float)(k - ctot) * __uint_as_float(T);
        atomicAdd(&accum[1], (double)neg);
        __threadfence();
        int prev = atomicAdd(done_cnt, 1);
        if (prev == BB - 1) {               // last block: finalize
            double a0 = atomicAdd(&accum[0], 0.0);
            double a1 = atomicAdd(&accum[1], 0.0);
            int N = 0;
            for (int bb = 0; bb < BB; ++bb) N += num_pos[bb];
            out[0] = (float)((a0 + a1) / (double)N);   // ALPHA = 1
        }
    }
}

extern "C" void kernel_launch(void* const* d_in, const int* in_sizes, int n_in,
                              void* d_out, int out_size, void* d_ws, size_t ws_size,
                              hipStream_t stream) {
    const float* loc_data  = (const float*)d_in[0];
    const float* conf_data = (const float*)d_in[1];
    const float* priors    = (const float*)d_in[2];
    const float* targets   = (const float*)d_in[3];

    char* ws = (char*)d_ws;
    // layout: [0,16) double accum[2]; [16,20) done_cnt; [32,288) int num_pos[64];
    //         [512,8704) u64 g_best[64*16]; [8704, +BB*PP) u8 conf_t;
    //         then float lcm[BB*PP]
    double* accum = (double*)ws;
    int* done_cnt = (int*)(ws + 16);
    int* num_pos = (int*)(ws + 32);
    unsigned long long* g_best = (unsigned long long*)(ws + 512);
    unsigned char* conf_t = (unsigned char*)(ws + 8704);
    float* lcm = (float*)(ws + 8704 + (size_t)BB * PP);

    hipMemsetAsync(ws, 0, 8704, stream);

    dim3 mg(NCHUNK, BB);
    k_matchA<<<mg, 256, 0, stream>>>(priors, targets, g_best);
    k_matchB<<<mg, 256, 0, stream>>>(loc_data, priors, targets, g_best,
                                     conf_t, num_pos, accum);

    k_conf<<<(BB * PP) / 256, 256, 0, stream>>>(conf_data, conf_t, lcm, accum);

    k_topk<<<BB, TK_THREADS, 0, stream>>>(lcm, num_pos, accum, done_cnt,
                                          (float*)d_out);
}